// Round 13
// baseline (244.239 us; speedup 1.0000x reference)
//
#include <hip/hip_runtime.h>
#include <hip/hip_fp16.h>

#define N_NODES   100000
#define N_EDGES   3200000
#define N_FEAT    128
#define HIDDEN    16
#define N_CLASSES 10
#define N_GRAPHS  64

#define NBUCK     391          // ceil(N_NODES/256), bucket = dst >> 8
#define SLOT      64           // stage capacity per (block,bucket) cell (mean 21, >9 sigma)
#define SLOTN     96           // fixed CSR capacity per node (mean deg 32, >11 sigma)
#define BINA_EPB  8192         // edges per block in k_binA (512 thr x 16)
#define BINA_BLOCKS ((N_EDGES + BINA_EPB - 1) / BINA_EPB)   // 391

// Workspace layout (4-byte units):
//   pooled : [0,        1024)       float [64][16], zeroed by k_binA block 0
//   dinv   : [1024,     101024)     float
//   be     : [101024,   301024)     int2 per node: (beg, end) into srcs
//   gcnt   : [301024,   453920)     int [391][391] per-(block,bucket) counts
//   srcs   : [453920,   10063136)   int, fixed-capacity CSR: node*96 base
//   stage  : [10063136, 19847520)   int [391][391][SLOT] packed (src<<8 | dst&255)
//   h1h    : [10063136, 10463136)   __half [N][16] (x@W1)*dinv (overlays stage)
//   h2h    : [10463136, 10863136)   __half [N][16] layer-2 feats, c>=10 zero
// total ~79.4 MB

// Single-pass binning: per-(block,bucket) fixed stage cells, LDS cursor only.
// int4 edge loads (4 edges/thread/pass); counts derived as cursor-base after.
// Block 0 also zeroes the pooled accumulator (used much later by k_agg2p).
__global__ __launch_bounds__(512) void k_binA(const int* __restrict__ src,
                                              const int* __restrict__ dst,
                                              int* __restrict__ gcnt,
                                              int* __restrict__ stage,
                                              float* __restrict__ pooled) {
    __shared__ int curb[NBUCK];
    int tid = threadIdx.x;
    int cellbase = blockIdx.x * NBUCK;
    for (int t = tid; t < NBUCK; t += 512) curb[t] = (cellbase + t) * SLOT;
    if (blockIdx.x == 0) { pooled[tid] = 0.f; pooled[tid + 512] = 0.f; }
    __syncthreads();
    long long base = (long long)blockIdx.x * BINA_EPB;
#pragma unroll
    for (int p = 0; p < 4; ++p) {
        long long e0 = base + p * 2048 + tid * 4;   // N_EDGES % 4 == 0
        if (e0 < N_EDGES) {
            int4 s4 = *(const int4*)&src[e0];
            int4 d4 = *(const int4*)&dst[e0];
            int p0 = atomicAdd(&curb[d4.x >> 8], 1);
            int p1 = atomicAdd(&curb[d4.y >> 8], 1);
            int p2 = atomicAdd(&curb[d4.z >> 8], 1);
            int p3 = atomicAdd(&curb[d4.w >> 8], 1);
            stage[p0] = (s4.x << 8) | (d4.x & 255);
            stage[p1] = (s4.y << 8) | (d4.y & 255);
            stage[p2] = (s4.z << 8) | (d4.z & 255);
            stage[p3] = (s4.w << 8) | (d4.w & 255);
        }
    }
    __syncthreads();
    for (int t = tid; t < NBUCK; t += 512)
        gcnt[cellbase + t] = curb[t] - (cellbase + t) * SLOT;
}

// One block per bucket, SINGLE pass: place each staged edge directly at its
// node's fixed-capacity CSR row (srcs[node*96 + cursor]); no histogram, no
// scan. be/dinv fall out of the final LDS cursors.
__global__ __launch_bounds__(1024) void k_binB(const int* __restrict__ gcnt,
                                               const int* __restrict__ stage,
                                               int2* __restrict__ be,
                                               float* __restrict__ dinv,
                                               int* __restrict__ srcs) {
    __shared__ int cur[256];
    __shared__ int scnt[BINA_BLOCKS];
    int b = blockIdx.x, tid = threadIdx.x;
    if (tid < 256) cur[tid] = 0;
    for (int s = tid; s < BINA_BLOCKS; s += 1024) scnt[s] = gcnt[s * NBUCK + b];
    __syncthreads();
    int stream = tid >> 5, ln = tid & 31;           // 32 streams x 32 lanes
    int nodebase = b * 256;
    for (int s = stream; s < BINA_BLOCKS; s += 32) {
        int c  = scnt[s];
        int sb = (s * NBUCK + b) * SLOT;
        for (int i = ln; i < c; i += 32) {
            int v = stage[sb + i];
            int nloc = v & 255;
            int p = atomicAdd(&cur[nloc], 1);
            srcs[(nodebase + nloc) * SLOTN + p] = v >> 8;
        }
    }
    __syncthreads();
    if (tid < 256) {
        int node = nodebase + tid;
        if (node < N_NODES) {
            int c = cur[tid];
            be[node]   = make_int2(node * SLOTN, node * SLOTN + c);
            dinv[node] = rsqrtf((float)c + 1.0f);
        }
    }
}

// 16 nodes per block: h1h[n][c] = fp16((x[n] @ W1)[c] * dinv[n]).
// W1 transposed into wT[16][132] so both operands read contiguously (b128).
__global__ __launch_bounds__(256) void k_gemm1(const float* __restrict__ x,
                                               const float* __restrict__ W1,
                                               const float* __restrict__ dinv,
                                               __half* __restrict__ h1h) {
    __shared__ float wT[16][132];          // 8.25 KB, pad 132 breaks bank aliasing
    __shared__ float xs[16 * N_FEAT];      // 8 KB
    __shared__ float ds[16];
    int tid  = threadIdx.x;
    int base = blockIdx.x * 16;
    if (tid < 16) ds[tid] = dinv[base + tid];
    const float4* w4 = (const float4*)W1;
    float4 wa = w4[tid], wb = w4[256 + tid];
    {
        int r = tid >> 2, cb = (tid & 3) * 4;
        wT[cb + 0][r] = wa.x; wT[cb + 1][r] = wa.y;
        wT[cb + 2][r] = wa.z; wT[cb + 3][r] = wa.w;
        int r2 = r + 64;
        wT[cb + 0][r2] = wb.x; wT[cb + 1][r2] = wb.y;
        wT[cb + 2][r2] = wb.z; wT[cb + 3][r2] = wb.w;
    }
    const float4* x4 = (const float4*)(x + (long long)base * N_FEAT);
    float4*       xd = (float4*)xs;
    xd[tid]       = x4[tid];
    xd[256 + tid] = x4[256 + tid];
    __syncthreads();
    int n = tid >> 4, c = tid & 15;
    const float4* xv = (const float4*)&xs[n * N_FEAT];
    const float4* wv = (const float4*)&wT[c][0];
    float acc = 0.f;
#pragma unroll
    for (int k4 = 0; k4 < 32; ++k4) {
        float4 a = xv[k4], w = wv[k4];
        acc += a.x * w.x + a.y * w.y + a.z * w.z + a.w * w.w;
    }
    h1h[(base + n) * HIDDEN + c] = __float2half(acc * ds[n]);
}

#define NT(p) __builtin_nontemporal_load(p)

// Edge gather core: 16-lane node group = 8 edge-slots x 2 halves.
// Per round the group covers 8 edges; each lane loads 16B (8 halves =
// channels h*8..h*8+7) of its edge. acc[8] per lane; 2-round software
// pipeline keeps 2 gathers + 2 src loads in flight per lane.
#define GATHER_DEF(TBL)                                                       \
    float acc[8];                                                             \
    _Pragma("unroll") for (int q = 0; q < 8; ++q) acc[q] = 0.f;               \
    {                                                                         \
        int ne = end - beg;                                                   \
        int nr = ne >> 3;                                                     \
        int j  = beg + k;                                                     \
        int npair = nr >> 1;                                                  \
        if (npair > 0) {                                                      \
            int sA = NT(&srcs[j]), sB = NT(&srcs[j + 8]);                     \
            for (int p = 1; p < npair; ++p) {                                 \
                int sC = NT(&srcs[j + 16]), sD = NT(&srcs[j + 24]);           \
                GACC(TBL, sA); GACC(TBL, sB);                                 \
                sA = sC; sB = sD; j += 16;                                    \
            }                                                                 \
            GACC(TBL, sA); GACC(TBL, sB); j += 16;                            \
        }                                                                     \
        if (nr & 1) { int sA = NT(&srcs[j]); GACC(TBL, sA); j += 8; }         \
        if (k < (ne & 7)) { int sA = NT(&srcs[j]); GACC(TBL, sA); }           \
    }                                                                         \
    _Pragma("unroll") for (int m = 2; m <= 8; m <<= 1) {                      \
        _Pragma("unroll") for (int q = 0; q < 8; ++q)                         \
            acc[q] += __shfl_xor(acc[q], m, 64);                              \
    }

#define GACC(TBL, S) {                                                        \
    float4 g_ = *(const float4*)(&TBL[(S) * 16 + h * 8]);                     \
    const __half2* hp_ = (const __half2*)&g_;                                 \
    float2 v0_ = __half22float2(hp_[0]);                                      \
    float2 v1_ = __half22float2(hp_[1]);                                      \
    float2 v2_ = __half22float2(hp_[2]);                                      \
    float2 v3_ = __half22float2(hp_[3]);                                      \
    acc[0] += v0_.x; acc[1] += v0_.y; acc[2] += v1_.x; acc[3] += v1_.y;       \
    acc[4] += v2_.x; acc[5] += v2_.y; acc[6] += v3_.x; acc[7] += v3_.y; }

// Fused: CSR gather of layer-1 aggregation + bias + ReLU + @W2 + dinv scale.
__global__ __launch_bounds__(256) void k_agg1(const int2* __restrict__ be,
                                              const int* __restrict__ srcs,
                                              const float* __restrict__ dinv,
                                              const __half* __restrict__ h1h,
                                              const float* __restrict__ b1,
                                              const float* __restrict__ W2,
                                              __half* __restrict__ h2h) {
    __shared__ float r_s[16][17];
    __shared__ float w2s[HIDDEN * N_CLASSES];
    int tid = threadIdx.x;
    if (tid < HIDDEN * N_CLASSES) w2s[tid] = W2[tid];
    int nl = tid >> 4, l = tid & 15, k = l >> 1, h = l & 1;
    int n  = blockIdx.x * 16 + nl;
    int2 bn = be[n];
    int beg = bn.x, end = bn.y;
    GATHER_DEF(h1h)
    if (l < 2) {
#pragma unroll
        for (int q = 0; q < 8; ++q) r_s[nl][h * 8 + q] = acc[q];
    }
    __syncthreads();
    float dn   = dinv[n];
    float self = __half2float(h1h[n * 16 + l]);
    float val  = fmaxf(dn * (r_s[nl][l] + self) + b1[l], 0.f);
    __syncthreads();
    r_s[nl][l] = val;
    __syncthreads();
    float o = 0.f;
    if (l < N_CLASSES) {
#pragma unroll
        for (int q = 0; q < HIDDEN; ++q) o += r_s[nl][q] * w2s[q * N_CLASSES + l];
        o *= dn;
    }
    h2h[n * 16 + l] = __float2half(o);     // l>=10 stores 0
}

// CSR gather of layer-2 aggregation, fused with graph pooling.
__global__ __launch_bounds__(256) void k_agg2p(const int2* __restrict__ be,
                                               const int* __restrict__ srcs,
                                               const float* __restrict__ dinv,
                                               const __half* __restrict__ h2h,
                                               const int* __restrict__ batch,
                                               float* __restrict__ pooled) {
    __shared__ float red[16][17];
    int tid = threadIdx.x;
    int nl = tid >> 4, l = tid & 15, k = l >> 1, h = l & 1;
    int nbase = blockIdx.x * 16;
    int n  = nbase + nl;
    int2 bn = be[n];
    int beg = bn.x, end = bn.y;
    GATHER_DEF(h2h)
    if (l < 2) {
#pragma unroll
        for (int q = 0; q < 8; ++q) red[nl][h * 8 + q] = acc[q];
    }
    __syncthreads();
    float self = __half2float(h2h[n * 16 + l]);
    float o = dinv[n] * (red[nl][l] + self);   // l>=10: table is 0 -> o=0
    __syncthreads();

    int g0  = batch[nbase];
    int g15 = batch[nbase + 15];
    if (g0 == g15) {                 // uniform branch: whole block one graph
        red[nl][l] = o;
        __syncthreads();
#pragma unroll
        for (int s = 8; s > 0; s >>= 1) {
            if (nl < s) red[nl][l] += red[nl + s][l];
            __syncthreads();
        }
        if (tid < N_CLASSES) atomicAdd(&pooled[g0 * 16 + tid], red[0][tid]);
    } else {                         // graph boundary inside block (rare)
        if (l < N_CLASSES) atomicAdd(&pooled[batch[n] * 16 + l], o);
    }
}

// one block, one thread per graph: counts via binary search on sorted batch,
// mean + b2, log_softmax -> out.
__global__ __launch_bounds__(64) void k_final(const float* __restrict__ pooled,
                                              const float* __restrict__ b2,
                                              const int* __restrict__ batch,
                                              float* __restrict__ out) {
    int g = threadIdx.x;
    if (g >= N_GRAPHS) return;
    int lo = 0, hi = N_NODES;
    while (lo < hi) { int m = (lo + hi) >> 1; if (batch[m] < g) lo = m + 1; else hi = m; }
    int start = lo;
    lo = 0; hi = N_NODES;
    while (lo < hi) { int m = (lo + hi) >> 1; if (batch[m] < g + 1) lo = m + 1; else hi = m; }
    int cnt = lo - start;

    float v[N_CLASSES];
    if (cnt > 0) {
        float inv = 1.f / (float)cnt;
#pragma unroll
        for (int j = 0; j < N_CLASSES; ++j) v[j] = pooled[g * 16 + j] * inv + b2[j];
    } else {
#pragma unroll
        for (int j = 0; j < N_CLASSES; ++j) v[j] = 0.f;
    }
    float m = v[0];
#pragma unroll
    for (int j = 1; j < N_CLASSES; ++j) m = fmaxf(m, v[j]);
    float l = 0.f;
#pragma unroll
    for (int j = 0; j < N_CLASSES; ++j) l += expf(v[j] - m);
    l = logf(l);
#pragma unroll
    for (int j = 0; j < N_CLASSES; ++j) out[g * N_CLASSES + j] = v[j] - m - l;
}

extern "C" void kernel_launch(void* const* d_in, const int* in_sizes, int n_in,
                              void* d_out, int out_size, void* d_ws, size_t ws_size,
                              hipStream_t stream) {
    const float* x     = (const float*)d_in[0];
    const int*   edge  = (const int*)d_in[1];   // [2, E]
    const int*   batch = (const int*)d_in[2];
    const float* W1    = (const float*)d_in[3];
    const float* b1    = (const float*)d_in[4];
    const float* W2    = (const float*)d_in[5];
    const float* b2    = (const float*)d_in[6];
    float* out = (float*)d_out;
    float* ws  = (float*)d_ws;

    float*  pooled = ws;                        // [0, 1024)
    float*  dinv   = ws + 1024;                 // [1024, 101024)
    int2*   be     = (int2*)(ws + 101024);      // [101024, 301024)
    int*    gcnt   = (int*)(ws + 301024);       // [301024, 453920) 391*391
    int*    srcs   = (int*)(ws + 453920);       // 100096*96 fixed-capacity CSR
    int*    stage  = (int*)(ws + 10063136);     // [391][391][SLOT]
    __half* h1h    = (__half*)(ws + 10063136);  // overlays stage (dead after binB)
    __half* h2h    = (__half*)(ws + 10463136);

    const int* srcp = edge;
    const int* dstp = edge + N_EDGES;

    k_binA<<<BINA_BLOCKS, 512, 0, stream>>>(srcp, dstp, gcnt, stage, pooled);
    k_binB<<<NBUCK, 1024, 0, stream>>>(gcnt, stage, be, dinv, srcs);
    k_gemm1<<<N_NODES / 16, 256, 0, stream>>>(x, W1, dinv, h1h);
    k_agg1<<<N_NODES / 16, 256, 0, stream>>>(be, srcs, dinv, h1h, b1, W2, h2h);
    k_agg2p<<<N_NODES / 16, 256, 0, stream>>>(be, srcs, dinv, h2h, batch, pooled);
    k_final<<<1, 64, 0, stream>>>(pooled, b2, batch, out);
}

// Round 14
// 227.563 us; speedup vs baseline: 1.0733x; 1.0733x over previous
//
#include <hip/hip_runtime.h>
#include <hip/hip_fp16.h>

#define N_NODES   100000
#define N_EDGES   3200000
#define N_FEAT    128
#define HIDDEN    16
#define N_CLASSES 10
#define N_GRAPHS  64

#define NBUCK     391          // ceil(N_NODES/256), bucket = dst >> 8
#define CAP       9216         // compact CSR capacity per bucket (mean 8192, +11 sigma)
#define SLOT      64           // stage capacity per (block,bucket) cell (mean 21, >9 sigma)
#define ROWCAP    88           // LDS row capacity per node (mean deg 32, ~10 sigma)
#define BINA_EPB  8192         // edges per block in k_binA (1024 thr x 8)
#define BINA_BLOCKS ((N_EDGES + BINA_EPB - 1) / BINA_EPB)   // 391

// Workspace layout (4-byte units):
//   pooled : [0,        1024)      float [64][16], zeroed by k_binA block 0
//   dinv   : [1024,     101024)    float
//   be     : [101024,   301024)    int2 per node: (beg, end) into srcs
//   gcnt   : [301024,   454912)    int [391][391] per-(block,bucket) counts
//   srcs   : [454912,   4058368)   int, compact CSR rows at bucket base b*CAP
//   stage  : [4058368,  13842752)  int [391][391][SLOT] packed (src<<8 | dst&255)
//   h1h    : [4058368,  4858368)   __half [N][16] (x@W1)*dinv (overlays stage)
//   h2h    : [4858368,  5658368)   __half [N][16] layer-2 feats, c>=10 zero
// total ~55.4 MB

// Single-pass binning: per-(block,bucket) fixed stage cells, LDS cursor only.
// 1024 threads (2x the waves of R13's 512 -- binA is latency-bound and wave
// count was the measured invariant). int4 edge loads, 8 edges/thread.
// Block 0 also zeroes the pooled accumulator (used much later by k_agg2p).
__global__ __launch_bounds__(1024) void k_binA(const int* __restrict__ src,
                                               const int* __restrict__ dst,
                                               int* __restrict__ gcnt,
                                               int* __restrict__ stage,
                                               float* __restrict__ pooled) {
    __shared__ int curb[NBUCK];
    int tid = threadIdx.x;
    int cellbase = blockIdx.x * NBUCK;
    for (int t = tid; t < NBUCK; t += 1024) curb[t] = (cellbase + t) * SLOT;
    if (blockIdx.x == 0) pooled[tid] = 0.f;       // 64*16 = 1024 floats
    __syncthreads();
    long long base = (long long)blockIdx.x * BINA_EPB;
#pragma unroll
    for (int p = 0; p < 2; ++p) {
        long long e0 = base + p * 4096 + tid * 4;   // N_EDGES % 4 == 0
        if (e0 < N_EDGES) {
            int4 s4 = *(const int4*)&src[e0];
            int4 d4 = *(const int4*)&dst[e0];
            int p0 = atomicAdd(&curb[d4.x >> 8], 1);
            int p1 = atomicAdd(&curb[d4.y >> 8], 1);
            int p2 = atomicAdd(&curb[d4.z >> 8], 1);
            int p3 = atomicAdd(&curb[d4.w >> 8], 1);
            stage[p0] = (s4.x << 8) | (d4.x & 255);
            stage[p1] = (s4.y << 8) | (d4.y & 255);
            stage[p2] = (s4.z << 8) | (d4.z & 255);
            stage[p3] = (s4.w << 8) | (d4.w & 255);
        }
    }
    __syncthreads();
    for (int t = tid; t < NBUCK; t += 1024)
        gcnt[cellbase + t] = curb[t] - (cellbase + t) * SLOT;
}

// One block per bucket, single stage pass: place each edge into its node's
// LDS row, then scan + coalesced compact write-out to srcs[b*CAP ...).
// be/dinv fall out of the LDS cursors. 90KB LDS -> 1 block/CU, 16 waves.
__global__ __launch_bounds__(1024) void k_binB(const int* __restrict__ gcnt,
                                               const int* __restrict__ stage,
                                               int2* __restrict__ be,
                                               float* __restrict__ dinv,
                                               int* __restrict__ srcs) {
    __shared__ int rows[256][ROWCAP];               // 90 KB
    __shared__ int cur[256];
    __shared__ int excl[256];
    __shared__ int scnt[BINA_BLOCKS];
    int b = blockIdx.x, tid = threadIdx.x;
    if (tid < 256) cur[tid] = 0;
    for (int s = tid; s < BINA_BLOCKS; s += 1024) scnt[s] = gcnt[s * NBUCK + b];
    __syncthreads();
    int stream = tid >> 5, ln = tid & 31;           // 32 streams x 32 lanes
    for (int s = stream; s < BINA_BLOCKS; s += 32) {
        int c  = scnt[s];
        int sb = (s * NBUCK + b) * SLOT;
        for (int i = ln; i < c; i += 32) {
            int v = stage[sb + i];
            int nloc = v & 255;
            int p = atomicAdd(&cur[nloc], 1);
            rows[nloc][p] = v >> 8;
        }
    }
    __syncthreads();
    int c = 0;
    if (tid < 256) { c = cur[tid]; excl[tid] = c; }
    __syncthreads();
    for (int o = 1; o < 256; o <<= 1) {
        int a = 0;
        if (tid < 256 && tid >= o) a = excl[tid - o];
        __syncthreads();
        if (tid < 256) excl[tid] += a;
        __syncthreads();
    }
    int sbase = b * CAP;
    if (tid < 256) {
        int ex = excl[tid] - c;
        int node = b * 256 + tid;
        if (node < N_NODES) {
            be[node]   = make_int2(sbase + ex, sbase + ex + c);
            dinv[node] = rsqrtf((float)c + 1.0f);
        }
    }
    __syncthreads();
    // compact write-out: 4 threads per node, dense sequential global writes
    int g = tid >> 2, j = tid & 3;
    int cg = cur[g];
    int ob = sbase + excl[g] - cg;
    for (int i = j; i < cg; i += 4) srcs[ob + i] = rows[g][i];
}

// 16 nodes per block: h1h[n][c] = fp16((x[n] @ W1)[c] * dinv[n]).
// W1 transposed into wT[16][132] so both operands read contiguously (b128).
__global__ __launch_bounds__(256) void k_gemm1(const float* __restrict__ x,
                                               const float* __restrict__ W1,
                                               const float* __restrict__ dinv,
                                               __half* __restrict__ h1h) {
    __shared__ float wT[16][132];          // 8.25 KB, pad 132 breaks bank aliasing
    __shared__ float xs[16 * N_FEAT];      // 8 KB
    __shared__ float ds[16];
    int tid  = threadIdx.x;
    int base = blockIdx.x * 16;
    if (tid < 16) ds[tid] = dinv[base + tid];
    const float4* w4 = (const float4*)W1;
    float4 wa = w4[tid], wb = w4[256 + tid];
    {
        int r = tid >> 2, cb = (tid & 3) * 4;
        wT[cb + 0][r] = wa.x; wT[cb + 1][r] = wa.y;
        wT[cb + 2][r] = wa.z; wT[cb + 3][r] = wa.w;
        int r2 = r + 64;
        wT[cb + 0][r2] = wb.x; wT[cb + 1][r2] = wb.y;
        wT[cb + 2][r2] = wb.z; wT[cb + 3][r2] = wb.w;
    }
    const float4* x4 = (const float4*)(x + (long long)base * N_FEAT);
    float4*       xd = (float4*)xs;
    xd[tid]       = x4[tid];
    xd[256 + tid] = x4[256 + tid];
    __syncthreads();
    int n = tid >> 4, c = tid & 15;
    const float4* xv = (const float4*)&xs[n * N_FEAT];
    const float4* wv = (const float4*)&wT[c][0];
    float acc = 0.f;
#pragma unroll
    for (int k4 = 0; k4 < 32; ++k4) {
        float4 a = xv[k4], w = wv[k4];
        acc += a.x * w.x + a.y * w.y + a.z * w.z + a.w * w.w;
    }
    h1h[(base + n) * HIDDEN + c] = __float2half(acc * ds[n]);
}

#define NT(p) __builtin_nontemporal_load(p)

// Edge gather core: 16-lane node group = 8 edge-slots x 2 halves.
// Per round the group covers 8 edges; each lane loads 16B (8 halves =
// channels h*8..h*8+7) of its edge. acc[8] per lane; 2-round software
// pipeline keeps 2 gathers + 2 src loads in flight per lane.
#define GATHER_DEF(TBL)                                                       \
    float acc[8];                                                             \
    _Pragma("unroll") for (int q = 0; q < 8; ++q) acc[q] = 0.f;               \
    {                                                                         \
        int ne = end - beg;                                                   \
        int nr = ne >> 3;                                                     \
        int j  = beg + k;                                                     \
        int npair = nr >> 1;                                                  \
        if (npair > 0) {                                                      \
            int sA = NT(&srcs[j]), sB = NT(&srcs[j + 8]);                     \
            for (int p = 1; p < npair; ++p) {                                 \
                int sC = NT(&srcs[j + 16]), sD = NT(&srcs[j + 24]);           \
                GACC(TBL, sA); GACC(TBL, sB);                                 \
                sA = sC; sB = sD; j += 16;                                    \
            }                                                                 \
            GACC(TBL, sA); GACC(TBL, sB); j += 16;                            \
        }                                                                     \
        if (nr & 1) { int sA = NT(&srcs[j]); GACC(TBL, sA); j += 8; }         \
        if (k < (ne & 7)) { int sA = NT(&srcs[j]); GACC(TBL, sA); }           \
    }                                                                         \
    _Pragma("unroll") for (int m = 2; m <= 8; m <<= 1) {                      \
        _Pragma("unroll") for (int q = 0; q < 8; ++q)                         \
            acc[q] += __shfl_xor(acc[q], m, 64);                              \
    }

#define GACC(TBL, S) {                                                        \
    float4 g_ = *(const float4*)(&TBL[(S) * 16 + h * 8]);                     \
    const __half2* hp_ = (const __half2*)&g_;                                 \
    float2 v0_ = __half22float2(hp_[0]);                                      \
    float2 v1_ = __half22float2(hp_[1]);                                      \
    float2 v2_ = __half22float2(hp_[2]);                                      \
    float2 v3_ = __half22float2(hp_[3]);                                      \
    acc[0] += v0_.x; acc[1] += v0_.y; acc[2] += v1_.x; acc[3] += v1_.y;       \
    acc[4] += v2_.x; acc[5] += v2_.y; acc[6] += v3_.x; acc[7] += v3_.y; }

// Fused: CSR gather of layer-1 aggregation + bias + ReLU + @W2 + dinv scale.
__global__ __launch_bounds__(256) void k_agg1(const int2* __restrict__ be,
                                              const int* __restrict__ srcs,
                                              const float* __restrict__ dinv,
                                              const __half* __restrict__ h1h,
                                              const float* __restrict__ b1,
                                              const float* __restrict__ W2,
                                              __half* __restrict__ h2h) {
    __shared__ float r_s[16][17];
    __shared__ float w2s[HIDDEN * N_CLASSES];
    int tid = threadIdx.x;
    if (tid < HIDDEN * N_CLASSES) w2s[tid] = W2[tid];
    int nl = tid >> 4, l = tid & 15, k = l >> 1, h = l & 1;
    int n  = blockIdx.x * 16 + nl;
    int2 bn = be[n];
    int beg = bn.x, end = bn.y;
    GATHER_DEF(h1h)
    if (l < 2) {
#pragma unroll
        for (int q = 0; q < 8; ++q) r_s[nl][h * 8 + q] = acc[q];
    }
    __syncthreads();
    float dn   = dinv[n];
    float self = __half2float(h1h[n * 16 + l]);
    float val  = fmaxf(dn * (r_s[nl][l] + self) + b1[l], 0.f);
    __syncthreads();
    r_s[nl][l] = val;
    __syncthreads();
    float o = 0.f;
    if (l < N_CLASSES) {
#pragma unroll
        for (int q = 0; q < HIDDEN; ++q) o += r_s[nl][q] * w2s[q * N_CLASSES + l];
        o *= dn;
    }
    h2h[n * 16 + l] = __float2half(o);     // l>=10 stores 0
}

// CSR gather of layer-2 aggregation, fused with graph pooling.
__global__ __launch_bounds__(256) void k_agg2p(const int2* __restrict__ be,
                                               const int* __restrict__ srcs,
                                               const float* __restrict__ dinv,
                                               const __half* __restrict__ h2h,
                                               const int* __restrict__ batch,
                                               float* __restrict__ pooled) {
    __shared__ float red[16][17];
    int tid = threadIdx.x;
    int nl = tid >> 4, l = tid & 15, k = l >> 1, h = l & 1;
    int nbase = blockIdx.x * 16;
    int n  = nbase + nl;
    int2 bn = be[n];
    int beg = bn.x, end = bn.y;
    GATHER_DEF(h2h)
    if (l < 2) {
#pragma unroll
        for (int q = 0; q < 8; ++q) red[nl][h * 8 + q] = acc[q];
    }
    __syncthreads();
    float self = __half2float(h2h[n * 16 + l]);
    float o = dinv[n] * (red[nl][l] + self);   // l>=10: table is 0 -> o=0
    __syncthreads();

    int g0  = batch[nbase];
    int g15 = batch[nbase + 15];
    if (g0 == g15) {                 // uniform branch: whole block one graph
        red[nl][l] = o;
        __syncthreads();
#pragma unroll
        for (int s = 8; s > 0; s >>= 1) {
            if (nl < s) red[nl][l] += red[nl + s][l];
            __syncthreads();
        }
        if (tid < N_CLASSES) atomicAdd(&pooled[g0 * 16 + tid], red[0][tid]);
    } else {                         // graph boundary inside block (rare)
        if (l < N_CLASSES) atomicAdd(&pooled[batch[n] * 16 + l], o);
    }
}

// one block, one thread per graph: counts via binary search on sorted batch,
// mean + b2, log_softmax -> out.
__global__ __launch_bounds__(64) void k_final(const float* __restrict__ pooled,
                                              const float* __restrict__ b2,
                                              const int* __restrict__ batch,
                                              float* __restrict__ out) {
    int g = threadIdx.x;
    if (g >= N_GRAPHS) return;
    int lo = 0, hi = N_NODES;
    while (lo < hi) { int m = (lo + hi) >> 1; if (batch[m] < g) lo = m + 1; else hi = m; }
    int start = lo;
    lo = 0; hi = N_NODES;
    while (lo < hi) { int m = (lo + hi) >> 1; if (batch[m] < g + 1) lo = m + 1; else hi = m; }
    int cnt = lo - start;

    float v[N_CLASSES];
    if (cnt > 0) {
        float inv = 1.f / (float)cnt;
#pragma unroll
        for (int j = 0; j < N_CLASSES; ++j) v[j] = pooled[g * 16 + j] * inv + b2[j];
    } else {
#pragma unroll
        for (int j = 0; j < N_CLASSES; ++j) v[j] = 0.f;
    }
    float m = v[0];
#pragma unroll
    for (int j = 1; j < N_CLASSES; ++j) m = fmaxf(m, v[j]);
    float l = 0.f;
#pragma unroll
    for (int j = 0; j < N_CLASSES; ++j) l += expf(v[j] - m);
    l = logf(l);
#pragma unroll
    for (int j = 0; j < N_CLASSES; ++j) out[g * N_CLASSES + j] = v[j] - m - l;
}

extern "C" void kernel_launch(void* const* d_in, const int* in_sizes, int n_in,
                              void* d_out, int out_size, void* d_ws, size_t ws_size,
                              hipStream_t stream) {
    const float* x     = (const float*)d_in[0];
    const int*   edge  = (const int*)d_in[1];   // [2, E]
    const int*   batch = (const int*)d_in[2];
    const float* W1    = (const float*)d_in[3];
    const float* b1    = (const float*)d_in[4];
    const float* W2    = (const float*)d_in[5];
    const float* b2    = (const float*)d_in[6];
    float* out = (float*)d_out;
    float* ws  = (float*)d_ws;

    float*  pooled = ws;                        // [0, 1024)
    float*  dinv   = ws + 1024;                 // [1024, 101024)
    int2*   be     = (int2*)(ws + 101024);      // [101024, 301024)
    int*    gcnt   = (int*)(ws + 301024);       // 391*391
    int*    srcs   = (int*)(ws + 454912);       // NBUCK*CAP compact CSR
    int*    stage  = (int*)(ws + 4058368);      // [391][391][SLOT]
    __half* h1h    = (__half*)(ws + 4058368);   // overlays stage (dead after binB)
    __half* h2h    = (__half*)(ws + 4858368);

    const int* srcp = edge;
    const int* dstp = edge + N_EDGES;

    k_binA<<<BINA_BLOCKS, 1024, 0, stream>>>(srcp, dstp, gcnt, stage, pooled);
    k_binB<<<NBUCK, 1024, 0, stream>>>(gcnt, stage, be, dinv, srcs);
    k_gemm1<<<N_NODES / 16, 256, 0, stream>>>(x, W1, dinv, h1h);
    k_agg1<<<N_NODES / 16, 256, 0, stream>>>(be, srcs, dinv, h1h, b1, W2, h2h);
    k_agg2p<<<N_NODES / 16, 256, 0, stream>>>(be, srcs, dinv, h2h, batch, pooled);
    k_final<<<1, 64, 0, stream>>>(pooled, b2, batch, out);
}